// Round 6
// baseline (191.189 us; speedup 1.0000x reference)
//
#include <hip/hip_runtime.h>

// Problem constants (from setup_inputs)
constexpr int NROIS = 2000;
constexpr int Hh = 100, Ww = 100, Cc = 256;
constexpr int CH = 7, CW = 7;
constexpr int NPIX  = NROIS * CH * CW;   // 98,000 output pixels
constexpr int NPAIR = NPIX / 2;          // 49,000 pixel-pairs (1 wave each)
constexpr int WPB   = 4;                 // waves per block
constexpr int NBLK  = NPAIR / WPB;       // 12,250 blocks (exact)
constexpr int NXCD  = 8;
constexpr int CHUNK_Q = NBLK / NXCD;     // 1531
constexpr int CHUNK_R = NBLK % NXCD;     // 2

constexpr int ROW_BYTES = Ww * Cc * 4;            // 102,400 B per fm row
constexpr int PIX_BYTES = Cc * 4;                 // 1,024 B per fm pixel
constexpr int IMG_BYTES = Hh * ROW_BYTES;         // 10,240,000 B per image
constexpr int OUTROI_BYTES = CH * CW * PIX_BYTES; // 50,176 B per roi output

typedef float floatx4 __attribute__((ext_vector_type(4)));

// ---------------------------------------------------------------------------
// Prepass (1 block): counting-sort ROIs by (image, y-band) AND precompute all
// per-ROI parameters into params[sorted_slot]:
//   P[0]=y0 P[1]=sy P[2]=x0 P[3]=sx  (in_y = y0+i*sy, in_x = x0+j*sx, math
//   order mirrors the reference exactly)  P[4]=fm byte base  P[5]=out byte base
// ---------------------------------------------------------------------------
constexpr int NBUCKET = 64;   // 8 images x 8 y-bands

__global__ __launch_bounds__(256) void roi_prep_kernel(
    const float* __restrict__ rois, float* __restrict__ params)
{
    __shared__ int cnt[NBUCKET];
    __shared__ int offs[NBUCKET];
    int t = threadIdx.x;
    if (t < NBUCKET) cnt[t] = 0;
    __syncthreads();

    for (int n = t; n < NROIS; n += 256) {
        const float* r = rois + (size_t)n * 5;
        int   b    = (int)r[0];
        float cy   = 0.5f * (r[2] + r[4]);                 // pixel units [0,100]
        int   band = min(7, max(0, (int)(cy * 0.08f)));
        atomicAdd(&cnt[b * 8 + band], 1);
    }
    __syncthreads();
    if (t == 0) {
        int s = 0;
        for (int k = 0; k < NBUCKET; ++k) { offs[k] = s; s += cnt[k]; }
    }
    __syncthreads();
    for (int n = t; n < NROIS; n += 256) {
        const float* r = rois + (size_t)n * 5;
        int   b    = (int)r[0];
        float cy   = 0.5f * (r[2] + r[4]);
        int   band = min(7, max(0, (int)(cy * 0.08f)));
        int   pos  = atomicAdd(&offs[b * 8 + band], 1);

        // Reference math order: normalize by /W,/H (IEEE divide), then *(dim-1)
        float x1 = r[1] / (float)Ww;
        float y1 = r[2] / (float)Hh;
        float x2 = r[3] / (float)Ww;
        float y2 = r[4] / (float)Hh;
        float* P = params + (size_t)pos * 8;
        P[0] = y1 * (float)(Hh - 1);                          // y0
        P[1] = (y2 - y1) * (float)(Hh - 1) / (float)(CH - 1); // sy
        P[2] = x1 * (float)(Ww - 1);                          // x0
        P[3] = (x2 - x1) * (float)(Ww - 1) / (float)(CW - 1); // sx
        ((int*)P)[4] = b * IMG_BYTES;
        ((int*)P)[5] = n * OUTROI_BYTES;
    }
}

// ---------------------------------------------------------------------------
// Main kernel: ONE WAVE PER PIXEL-PAIR. Lanes 0-31 -> pixel 2g, lanes 32-63
// -> pixel 2g+1; each lane covers 2 float4s (c8*16 and +512). Per-wave
// in-flight gathers 4 -> 8 (8 KB/wave), wave count 98k -> 49k, VALU-per-byte
// ~0.6x. Dependent chain unchanged: param load -> coord math -> gathers ->
// lerp -> nt store. Sorted order + bijective XCD chunking keeps cross-ROI
// reuse in per-XCD L2 (proven: FETCH 170 MB -> 64 MB).
// ---------------------------------------------------------------------------
__global__ __launch_bounds__(256) void roi_gather_kernel(
    const char* __restrict__ fm,      // [8,100,100,256] fp32 as bytes
    const float* __restrict__ params, // [2000][8] per sorted slot
    char* __restrict__ out)           // [2000,7,7,256] fp32 as bytes
{
    int blk  = blockIdx.x;
    int xcd  = blk & (NXCD - 1);
    int slot = blk >> 3;
    int work = (xcd < CHUNK_R ? xcd * (CHUNK_Q + 1)
                              : CHUNK_R * (CHUNK_Q + 1) + (xcd - CHUNK_R) * CHUNK_Q)
             + slot;

    int wave = work * WPB + (threadIdx.x >> 6);   // pair id [0, 49000)
    int half = (threadIdx.x >> 5) & 1;            // which pixel of the pair
    int c8   = threadIdx.x & 31;                  // float4-pair index (channels)

    int g   = wave * 2 + half;                    // sorted-space pixel id
    int s   = g / 49;                             // sorted roi slot (magic-mul)
    int pix = g - s * 49;
    int i   = pix / 7;
    int j   = pix - i * 7;

    const float* P = params + (size_t)s * 8;
    float y0 = P[0], sy = P[1], x0 = P[2], sx = P[3];
    int fmbase  = ((const int*)P)[4];
    int outbase = ((const int*)P)[5];

    float in_y = y0 + (float)i * sy;
    float in_x = x0 + (float)j * sx;

    bool valid = (in_y >= 0.f) && (in_y <= (float)(Hh - 1)) &&
                 (in_x >= 0.f) && (in_x <= (float)(Ww - 1));

    float fy = floorf(in_y), fx = floorf(in_x);
    float ly = in_y - fy,    lx = in_x - fx;
    int ty = max(0, min(Hh - 1, (int)fy));
    int by = max(0, min(Hh - 1, (int)ceilf(in_y)));
    int tx = max(0, min(Ww - 1, (int)fx));
    int bx = max(0, min(Ww - 1, (int)ceilf(in_x)));

    int laneoff = c8 * 16;                        // first 512B half of the pixel
    int rT = fmbase + ty * ROW_BYTES + laneoff;
    int rB = fmbase + by * ROW_BYTES + laneoff;
    int oTX = tx * PIX_BYTES, oBX = bx * PIX_BYTES;

    // 8 independent 16B loads per lane (2 channel-quads x 4 neighbors)
    floatx4 tl0 = *(const floatx4*)(fm + rT + oTX);
    floatx4 tr0 = *(const floatx4*)(fm + rT + oBX);
    floatx4 bl0 = *(const floatx4*)(fm + rB + oTX);
    floatx4 br0 = *(const floatx4*)(fm + rB + oBX);
    floatx4 tl1 = *(const floatx4*)(fm + rT + oTX + 512);
    floatx4 tr1 = *(const floatx4*)(fm + rT + oBX + 512);
    floatx4 bl1 = *(const floatx4*)(fm + rB + oTX + 512);
    floatx4 br1 = *(const floatx4*)(fm + rB + oBX + 512);

    floatx4 top0 = tl0 + (tr0 - tl0) * lx;
    floatx4 bot0 = bl0 + (br0 - bl0) * lx;
    floatx4 o0   = top0 + (bot0 - top0) * ly;
    floatx4 top1 = tl1 + (tr1 - tl1) * lx;
    floatx4 bot1 = bl1 + (br1 - bl1) * lx;
    floatx4 o1   = top1 + (bot1 - top1) * ly;
    o0 = valid ? o0 : (floatx4)0.f;
    o1 = valid ? o1 : (floatx4)0.f;

    // nt store: 98 MB output stream is never re-read; keep L2 for the fm.
    char* po = out + outbase + pix * PIX_BYTES + laneoff;
    __builtin_nontemporal_store(o0, (floatx4*)po);
    __builtin_nontemporal_store(o1, (floatx4*)(po + 512));
}

extern "C" void kernel_launch(void* const* d_in, const int* in_sizes, int n_in,
                              void* d_out, int out_size, void* d_ws, size_t ws_size,
                              hipStream_t stream) {
    const float* fm   = (const float*)d_in[0];   // [8,100,100,256] fp32
    const float* rois = (const float*)d_in[1];   // [2000,5] fp32
    char* out = (char*)d_out;                    // [2000,7,7,256] fp32
    float* params = (float*)d_ws;                // 2000*32 B = 64 KB workspace

    roi_prep_kernel<<<1, 256, 0, stream>>>(rois, params);
    roi_gather_kernel<<<NBLK, 256, 0, stream>>>((const char*)fm, params, out);
}

// Round 7
// 184.025 us; speedup vs baseline: 1.0389x; 1.0389x over previous
//
#include <hip/hip_runtime.h>

// Problem constants (from setup_inputs)
constexpr int NROIS = 2000;
constexpr int Hh = 100, Ww = 100, Cc = 256;
constexpr int CH = 7, CW = 7;
constexpr int C4 = Cc / 4;              // 64 float4 per pixel -> one wave-width
constexpr int NPIX = NROIS * CH * CW;   // 98,000 output pixels (1 wave each)
constexpr int WPB  = 4;                 // waves per block
constexpr int NBLK = NPIX / WPB;        // 24,500 blocks (exact)
constexpr int NXCD = 8;
constexpr int CHUNK_Q = NBLK / NXCD;    // 3062
constexpr int CHUNK_R = NBLK % NXCD;    // 4

constexpr int ROW_BYTES = Ww * Cc * 4;            // 102,400 B per fm row
constexpr int PIX_BYTES = Cc * 4;                 // 1,024 B per fm pixel
constexpr int IMG_BYTES = Hh * ROW_BYTES;         // 10,240,000 B per image
constexpr int OUTROI_BYTES = CH * CW * PIX_BYTES; // 50,176 B per roi output

typedef float floatx4 __attribute__((ext_vector_type(4)));

// ---------------------------------------------------------------------------
// Prepass (1 block): counting-sort ROIs by (image, y-band) AND precompute all
// per-ROI parameters into params[sorted_slot]:
//   P[0]=y0 P[1]=sy P[2]=x0 P[3]=sx  (in_y = y0+i*sy, in_x = x0+j*sx, math
//   order mirrors the reference exactly)  P[4]=fm byte base  P[5]=out byte base
// ---------------------------------------------------------------------------
constexpr int NBUCKET = 64;   // 8 images x 8 y-bands

__global__ __launch_bounds__(256) void roi_prep_kernel(
    const float* __restrict__ rois, float* __restrict__ params)
{
    __shared__ int cnt[NBUCKET];
    __shared__ int offs[NBUCKET];
    int t = threadIdx.x;
    if (t < NBUCKET) cnt[t] = 0;
    __syncthreads();

    for (int n = t; n < NROIS; n += 256) {
        const float* r = rois + (size_t)n * 5;
        int   b    = (int)r[0];
        float cy   = 0.5f * (r[2] + r[4]);                 // pixel units [0,100]
        int   band = min(7, max(0, (int)(cy * 0.08f)));
        atomicAdd(&cnt[b * 8 + band], 1);
    }
    __syncthreads();
    if (t == 0) {
        int s = 0;
        for (int k = 0; k < NBUCKET; ++k) { offs[k] = s; s += cnt[k]; }
    }
    __syncthreads();
    for (int n = t; n < NROIS; n += 256) {
        const float* r = rois + (size_t)n * 5;
        int   b    = (int)r[0];
        float cy   = 0.5f * (r[2] + r[4]);
        int   band = min(7, max(0, (int)(cy * 0.08f)));
        int   pos  = atomicAdd(&offs[b * 8 + band], 1);

        // Reference math order: normalize by /W,/H (IEEE divide), then *(dim-1)
        float x1 = r[1] / (float)Ww;
        float y1 = r[2] / (float)Hh;
        float x2 = r[3] / (float)Ww;
        float y2 = r[4] / (float)Hh;
        float* P = params + (size_t)pos * 8;
        P[0] = y1 * (float)(Hh - 1);                          // y0
        P[1] = (y2 - y1) * (float)(Hh - 1) / (float)(CH - 1); // sy
        P[2] = x1 * (float)(Ww - 1);                          // x0
        P[3] = (x2 - x1) * (float)(Ww - 1) / (float)(CW - 1); // sx
        ((int*)P)[4] = b * IMG_BYTES;
        ((int*)P)[5] = n * OUTROI_BYTES;
    }
}

// ---------------------------------------------------------------------------
// Main kernel: ONE WAVE PER OUTPUT PIXEL (R5 structure — measured fastest).
// Minimal dependent chain: uniform 32B param load -> 32-bit coord/addr math
// -> 4 independent 1KB gathers -> bilinear lerp -> PLAIN store.
// A/B vs R5: nt store -> plain store. Theory: the nt-store path caps at
// ~1.55 TB/s chip-wide (98 MB / 63 us, invariant across R3-R6 while every
// read-side parameter changed), pinning the kernel floor. Normal stores
// write-combine in L2 (harness fills sustain 6.5 TB/s that way). L2
// pollution concern is moot post-sort: active fm window per XCD ~1-2 MB.
// ---------------------------------------------------------------------------
__global__ __launch_bounds__(256) void roi_gather_kernel(
    const char* __restrict__ fm,      // [8,100,100,256] fp32 as bytes
    const float* __restrict__ params, // [2000][8] per sorted slot
    char* __restrict__ out)           // [2000,7,7,256] fp32 as bytes
{
    int blk  = blockIdx.x;
    int xcd  = blk & (NXCD - 1);
    int slot = blk >> 3;
    int work = (xcd < CHUNK_R ? xcd * (CHUNK_Q + 1)
                              : CHUNK_R * (CHUNK_Q + 1) + (xcd - CHUNK_R) * CHUNK_Q)
             + slot;

    // Wave-uniform pixel id -> scalar registers
    int g    = __builtin_amdgcn_readfirstlane(work * WPB + (threadIdx.x >> 6));
    int lane = threadIdx.x & (C4 - 1);

    int s   = g / 49;            // sorted roi slot (magic-mul div)
    int pix = g - s * 49;
    int i   = pix / 7;
    int j   = pix - i * 7;

    const float* P = params + (size_t)s * 8;
    float y0 = P[0], sy = P[1], x0 = P[2], sx = P[3];
    int fmbase  = ((const int*)P)[4];
    int outbase = ((const int*)P)[5];

    float in_y = y0 + (float)i * sy;
    float in_x = x0 + (float)j * sx;

    bool valid = (in_y >= 0.f) && (in_y <= (float)(Hh - 1)) &&
                 (in_x >= 0.f) && (in_x <= (float)(Ww - 1));

    float fy = floorf(in_y), fx = floorf(in_x);
    float ly = in_y - fy,    lx = in_x - fx;
    int ty = max(0, min(Hh - 1, (int)fy));
    int by = max(0, min(Hh - 1, (int)ceilf(in_y)));
    int tx = max(0, min(Ww - 1, (int)fx));
    int bx = max(0, min(Ww - 1, (int)ceilf(in_x)));

    int laneoff = lane * 16;
    int rT = fmbase + ty * ROW_BYTES + laneoff;
    int rB = fmbase + by * ROW_BYTES + laneoff;
    int oTX = tx * PIX_BYTES, oBX = bx * PIX_BYTES;

    floatx4 tl = *(const floatx4*)(fm + rT + oTX);
    floatx4 tr = *(const floatx4*)(fm + rT + oBX);
    floatx4 bl = *(const floatx4*)(fm + rB + oTX);
    floatx4 br = *(const floatx4*)(fm + rB + oBX);

    floatx4 top = tl + (tr - tl) * lx;
    floatx4 bot = bl + (br - bl) * lx;
    floatx4 o   = top + (bot - top) * ly;
    o = valid ? o : (floatx4)0.f;

    // PLAIN store (the A/B variable): let L2 write-combine the output stream.
    *(floatx4*)(out + outbase + pix * PIX_BYTES + laneoff) = o;
}

extern "C" void kernel_launch(void* const* d_in, const int* in_sizes, int n_in,
                              void* d_out, int out_size, void* d_ws, size_t ws_size,
                              hipStream_t stream) {
    const float* fm   = (const float*)d_in[0];   // [8,100,100,256] fp32
    const float* rois = (const float*)d_in[1];   // [2000,5] fp32
    char* out = (char*)d_out;                    // [2000,7,7,256] fp32
    float* params = (float*)d_ws;                // 2000*32 B = 64 KB workspace

    roi_prep_kernel<<<1, 256, 0, stream>>>(rois, params);
    roi_gather_kernel<<<NBLK, 256, 0, stream>>>((const char*)fm, params, out);
}